// Round 4
// baseline (357.964 us; speedup 1.0000x reference)
//
#include <hip/hip_runtime.h>
#include <hip/hip_bf16.h>

#define NA   65536
#define DIN  512
#define DOUT 512
#define NE   8
#define NS   64
#define CAP  1280   // per-system perm capacity (count ~ 1024 +- 32)
#define BM   128
#define BN   128
#define BK   32
#define TPS  (CAP / BM)   // row tiles per system = 10
#define NKT  (DIN / BK)   // 16 K-tiles
#define CSTR 32           // counts stride (ints): one 128B line per system

typedef __attribute__((ext_vector_type(8))) __bf16 bf16x8;
typedef __attribute__((ext_vector_type(4))) float floatx4;

__device__ __forceinline__ void async_load16(const void* g, void* l) {
  __builtin_amdgcn_global_load_lds(
      (__attribute__((address_space(1))) void*)(void*)g,
      (__attribute__((address_space(3))) void*)l,
      16, 0, 0);
}

// Bucket atoms by system. counts[] zeroed by hipMemsetAsync; padded to one
// cache line per system so the 16K global atomics don't serialize on 2 lines.
__global__ void scatter_kernel(const int* __restrict__ bidx,
                               int* __restrict__ counts,
                               int* __restrict__ perm) {
  __shared__ int hist[NS];
  __shared__ int base[NS];
  int t = threadIdx.x;
  if (t < NS) hist[t] = 0;
  __syncthreads();
  int n = blockIdx.x * 256 + t;
  int s = bidx[n];
  int rank = atomicAdd(&hist[s], 1);
  __syncthreads();
  if (t < NS && hist[t] > 0) base[t] = atomicAdd(&counts[t * CSTR], hist[t]);
  __syncthreads();
  perm[s * CAP + base[s] + rank] = n;
}

// mixedW[s][o][i] = sum_e coeff[s][e] * W[e][o][i], bf16 K-contiguous.
// Grid (128, 8): 1024 blocks. Each block caches a 2048-elem chunk of all 8
// experts in registers, reuses across 8 systems.
__global__ void mixw_kernel(const float* __restrict__ W,
                            const float* __restrict__ coeff,
                            ushort* __restrict__ mixedW) {
  int t = threadIdx.x;
  int base = blockIdx.x * 2048 + t * 8;
  float w[NE][8];
#pragma unroll
  for (int e = 0; e < NE; e++) {
    const float4* p = (const float4*)(W + e * (DOUT * DIN) + base);
    float4 a = p[0], b = p[1];
    w[e][0] = a.x; w[e][1] = a.y; w[e][2] = a.z; w[e][3] = a.w;
    w[e][4] = b.x; w[e][5] = b.y; w[e][6] = b.z; w[e][7] = b.w;
  }
  int s0 = blockIdx.y * 8;
  for (int si = 0; si < 8; si++) {
    int s = s0 + si;
    float o[8] = {0, 0, 0, 0, 0, 0, 0, 0};
#pragma unroll
    for (int e = 0; e < NE; e++) {
      float c = coeff[s * NE + e];  // wave-uniform scalar load
#pragma unroll
      for (int j = 0; j < 8; j++) o[j] += c * w[e][j];
    }
    union { bf16x8 v; uint4 u; } cv;
#pragma unroll
    for (int j = 0; j < 8; j++) cv.v[j] = (__bf16)o[j];
    *(uint4*)(mixedW + (size_t)s * (DOUT * DIN) + base) = cv.u;
  }
}

// Grouped GEMM, depth-3 pipeline (T3+T4): 3 LDS buffers; tiles t+1,t+2 always
// in flight; steady-state s_waitcnt vmcnt(12) (= 2 tiles x 6 loads/wave) so
// tile t is resident while 2 tiles' loads span the barriers (~2 iters to
// cover ~900cy HBM latency; depth-1 was measured null).
// A is staged DIRECTLY from fp32 x via per-lane gathered global_load_lds
// (global source addr is per-lane; LDS dest is wave-uniform + lane*16),
// rows from clamped per-lane perm loads; f32->bf16 convert after ds_read.
// This removes the gather kernel and the 84MB xp buffer (workspace poison).
// B (bf16 mixedW) staged linearly as before.
__global__ __launch_bounds__(256) void gemm_kernel(
    const float* __restrict__ x, const ushort* __restrict__ mixedW,
    const int* __restrict__ perm, const int* __restrict__ counts,
    const float* __restrict__ bias, float* __restrict__ out) {
  // XCD-aware swizzle (T1): dispatch slot lin lands on XCD lin%8; give each
  // XCD a contiguous chunk of work ids so the 4 column-blocks sharing an
  // A-row-panel (and ~8 systems' B panels) hit the same L2. nwg%8==0.
  int nwg = gridDim.x * gridDim.y;          // 2560
  int lin = blockIdx.y * gridDim.x + blockIdx.x;
  int cpx = nwg >> 3;
  int work = (lin & 7) * cpx + (lin >> 3);  // bijective
  int bx = work & 3;                        // gridDim.x == 4
  int by = work >> 2;

  int s = by / TPS;
  int tt = by - s * TPS;
  int count = counts[s * CSTR];
  int r0 = tt * BM;
  if (r0 >= count) return;        // dead tile
  int rows = min(BM, count - r0);
  int n0 = bx * BN;

  __shared__ __align__(16) float  Alds[3][BM * BK];   // 3 x 16 KB fp32
  __shared__ __align__(16) ushort Blds[3][BN * BK];   // 3 x 8 KB bf16
  __shared__ int prow[BM];

  int tid = threadIdx.x;
  int lane = tid & 63;
  int wave = tid >> 6;

  if (tid < BM) prow[tid] = perm[s * CAP + r0 + min(tid, rows - 1)];

  // A staging map (fp32): wave-load j=0..3, region=j*4+wave covers 8 rows.
  // lane -> row = region*8 + lane/8, k-floats (lane&7)*4. Per-lane row gather.
  const float* aptr[4];
  int aoff[4];
#pragma unroll
  for (int j = 0; j < 4; j++) {
    int region = j * 4 + wave;
    int arow = region * 8 + (lane >> 3);
    int pr = perm[s * CAP + r0 + min(arow, rows - 1)];  // clamped: valid addr
    aptr[j] = x + (size_t)pr * DIN + (lane & 7) * 4;
    aoff[j] = region * 256;  // float units (1 KB per region)
  }
  // B staging map (bf16): wave-load j=0..1, region=j*4+wave covers 16 rows.
  const ushort* bptr[2];
  int boff[2];
#pragma unroll
  for (int j = 0; j < 2; j++) {
    int region = j * 4 + wave;
    int brow = region * 16 + (lane >> 2);
    bptr[j] = mixedW + (size_t)s * (DOUT * DIN) + (size_t)(n0 + brow) * DIN +
              (lane & 3) * 8;
    boff[j] = region * 512;  // ushort units
  }

  floatx4 acc[4][4];
#pragma unroll
  for (int mt = 0; mt < 4; mt++)
#pragma unroll
    for (int nt = 0; nt < 4; nt++) acc[mt][nt] = {0.f, 0.f, 0.f, 0.f};

  int wm = wave >> 1, wn = wave & 1;
  int m15 = lane & 15, quad = lane >> 4;

  __syncthreads();  // prow visible before anyone's epilogue; perm reads done

  // Prologue: stage tiles 0 and 1 (12 loads/wave outstanding).
#pragma unroll
  for (int t0 = 0; t0 < 2; t0++) {
#pragma unroll
    for (int j = 0; j < 4; j++)
      async_load16(aptr[j] + t0 * BK, Alds[t0] + aoff[j]);
#pragma unroll
    for (int j = 0; j < 2; j++)
      async_load16(bptr[j] + t0 * BK, Blds[t0] + boff[j]);
  }

  for (int t = 0; t < NKT; ++t) {
    if (t + 2 < NKT) {
      int nb = (t + 2) % 3;
#pragma unroll
      for (int j = 0; j < 4; j++)
        async_load16(aptr[j] + (t + 2) * BK, Alds[nb] + aoff[j]);
#pragma unroll
      for (int j = 0; j < 2; j++)
        async_load16(bptr[j] + (t + 2) * BK, Blds[nb] + boff[j]);
      asm volatile("s_waitcnt vmcnt(12)" ::: "memory");  // tile t landed
    } else if (t == NKT - 2) {
      asm volatile("s_waitcnt vmcnt(6)" ::: "memory");
    } else {
      asm volatile("s_waitcnt vmcnt(0)" ::: "memory");
    }
    __builtin_amdgcn_s_barrier();        // all waves' tile-t loads done
    __builtin_amdgcn_sched_barrier(0);   // no ds_read hoisted above barrier

    int cb = t % 3;
    bf16x8 af[4], bfm[4];
#pragma unroll
    for (int i = 0; i < 4; i++) {
      const float* ap = Alds[cb] + (wm * 64 + i * 16 + m15) * BK + quad * 8;
      floatx4 lo = *(const floatx4*)ap;
      floatx4 hi = *(const floatx4*)(ap + 4);
#pragma unroll
      for (int k = 0; k < 4; k++) {
        af[i][k] = (__bf16)lo[k];
        af[i][4 + k] = (__bf16)hi[k];
      }
      bfm[i] = *(const bf16x8*)(Blds[cb] + (wn * 64 + i * 16 + m15) * BK + quad * 8);
    }
#pragma unroll
    for (int mt = 0; mt < 4; mt++)
#pragma unroll
      for (int nt = 0; nt < 4; nt++)
        acc[mt][nt] = __builtin_amdgcn_mfma_f32_16x16x32_bf16(
            af[mt], bfm[nt], acc[mt][nt], 0, 0, 0);

    __builtin_amdgcn_sched_barrier(0);   // no ds_read sunk below barrier
    __builtin_amdgcn_s_barrier();        // all waves done reading buf t%3
  }

  // Epilogue: C/D layout col=lane&15 (o), row=quad*4+reg (x-row in tile)
  float bv[4];
#pragma unroll
  for (int nt = 0; nt < 4; nt++) bv[nt] = bias[n0 + wn * 64 + nt * 16 + m15];

#pragma unroll
  for (int mt = 0; mt < 4; mt++) {
    int rb = wm * 64 + mt * 16 + quad * 4;
    int pr[4];
#pragma unroll
    for (int r = 0; r < 4; r++) pr[r] = prow[rb + r];
#pragma unroll
    for (int nt = 0; nt < 4; nt++) {
      int col = n0 + wn * 64 + nt * 16 + m15;
#pragma unroll
      for (int r = 0; r < 4; r++) {
        if (rb + r < rows)
          out[(size_t)pr[r] * DOUT + col] = acc[mt][nt][r] + bv[nt];
      }
    }
  }
}

extern "C" void kernel_launch(void* const* d_in, const int* in_sizes, int n_in,
                              void* d_out, int out_size, void* d_ws,
                              size_t ws_size, hipStream_t stream) {
  const float* x     = (const float*)d_in[0];
  const float* coeff = (const float*)d_in[1];
  const int*   bidx  = (const int*)d_in[2];
  const float* W     = (const float*)d_in[3];
  const float* bias  = (const float*)d_in[4];
  float* out = (float*)d_out;

  char* ws = (char*)d_ws;
  int* counts    = (int*)ws;                                  // 8 KB (padded)
  int* perm      = (int*)(ws + NS * CSTR * 4);                // 320 KB
  ushort* mixedW = (ushort*)(ws + NS * CSTR * 4 + NS * CAP * 4);  // 33.5 MB
  // total workspace ~34 MB (was 118 MB): re-poison cost scales with ws size

  hipMemsetAsync(counts, 0, NS * CSTR * sizeof(int), stream);
  hipLaunchKernelGGL(scatter_kernel, dim3(NA / 256), dim3(256), 0, stream,
                     bidx, counts, perm);
  hipLaunchKernelGGL(mixw_kernel, dim3(DOUT * DIN / 2048, 8), dim3(256), 0,
                     stream, W, coeff, mixedW);
  hipLaunchKernelGGL(gemm_kernel, dim3(DOUT / BN, NS * TPS), dim3(256), 0,
                     stream, x, mixedW, perm, counts, bias, out);
}

// Round 6
// 343.442 us; speedup vs baseline: 1.0423x; 1.0423x over previous
//
#include <hip/hip_runtime.h>
#include <hip/hip_bf16.h>

#define NA   65536
#define DIN  512
#define DOUT 512
#define NE   8
#define NS   64
#define CAP  1280   // per-system perm capacity (count ~ 1024 +- 32)
#define BM   128
#define BN   128
#define BK   32
#define TPS  (CAP / BM)   // row tiles per system = 10
#define NKT  (DIN / BK)   // 16 K-tiles
#define CSTR 32           // counts stride (ints): one 128B line per system
#define TILE_US 4096      // ushorts per 8KB LDS tile (BM*BK)

typedef __attribute__((ext_vector_type(8))) __bf16 bf16x8;
typedef __attribute__((ext_vector_type(4))) float floatx4;

__device__ __forceinline__ void async_load16(const void* g, void* l) {
  __builtin_amdgcn_global_load_lds(
      (__attribute__((address_space(1))) void*)(void*)g,
      (__attribute__((address_space(3))) void*)l,
      16, 0, 0);
}

__device__ __forceinline__ int b3(int c) { return c >= 3 ? c - 3 : c; }

// Bucket atoms by system. counts[] zeroed by hipMemsetAsync; padded to one
// cache line per system so the global atomics don't serialize on 2 lines.
__global__ void scatter_kernel(const int* __restrict__ bidx,
                               int* __restrict__ counts,
                               int* __restrict__ perm) {
  __shared__ int hist[NS];
  __shared__ int base[NS];
  int t = threadIdx.x;
  if (t < NS) hist[t] = 0;
  __syncthreads();
  int n = blockIdx.x * 256 + t;
  int s = bidx[n];
  int rank = atomicAdd(&hist[s], 1);
  __syncthreads();
  if (t < NS && hist[t] > 0) base[t] = atomicAdd(&counts[t * CSTR], hist[t]);
  __syncthreads();
  perm[s * CAP + base[s] + rank] = n;
}

// mixedW[s][o][i] = sum_e coeff[s][e] * W[e][o][i], bf16 K-contiguous.
__global__ void mixw_kernel(const float* __restrict__ W,
                            const float* __restrict__ coeff,
                            ushort* __restrict__ mixedW) {
  int t = threadIdx.x;
  int base = blockIdx.x * 2048 + t * 8;
  float w[NE][8];
#pragma unroll
  for (int e = 0; e < NE; e++) {
    const float4* p = (const float4*)(W + e * (DOUT * DIN) + base);
    float4 a = p[0], b = p[1];
    w[e][0] = a.x; w[e][1] = a.y; w[e][2] = a.z; w[e][3] = a.w;
    w[e][4] = b.x; w[e][5] = b.y; w[e][6] = b.z; w[e][7] = b.w;
  }
  int s0 = blockIdx.y * 8;
  for (int si = 0; si < 8; si++) {
    int s = s0 + si;
    float o[8] = {0, 0, 0, 0, 0, 0, 0, 0};
#pragma unroll
    for (int e = 0; e < NE; e++) {
      float c = coeff[s * NE + e];
#pragma unroll
      for (int j = 0; j < 8; j++) o[j] += c * w[e][j];
    }
    union { bf16x8 v; uint4 u; } cv;
#pragma unroll
    for (int j = 0; j < 8; j++) cv.v[j] = (__bf16)o[j];
    *(uint4*)(mixedW + (size_t)s * (DOUT * DIN) + base) = cv.u;
  }
}

__device__ __forceinline__ void gload_a(const float* g0, const float* g1,
                                        int kt, float4& s0, float4& s1,
                                        float4& s2, float4& s3) {
  const float* a0 = g0 + kt * BK;
  const float* a1 = g1 + kt * BK;
  s0 = *(const float4*)(a0);
  s1 = *(const float4*)(a0 + 4);
  s2 = *(const float4*)(a1);
  s3 = *(const float4*)(a1 + 4);
}

__device__ __forceinline__ void cvt_write(ushort* Ab, int wo0, int wo1,
                                          const float4& s0, const float4& s1,
                                          const float4& s2, const float4& s3) {
  bf16x8 h;
  h[0] = (__bf16)s0.x; h[1] = (__bf16)s0.y; h[2] = (__bf16)s0.z; h[3] = (__bf16)s0.w;
  h[4] = (__bf16)s1.x; h[5] = (__bf16)s1.y; h[6] = (__bf16)s1.z; h[7] = (__bf16)s1.w;
  *(bf16x8*)(Ab + wo0) = h;
  bf16x8 g;
  g[0] = (__bf16)s2.x; g[1] = (__bf16)s2.y; g[2] = (__bf16)s2.z; g[3] = (__bf16)s2.w;
  g[4] = (__bf16)s3.x; g[5] = (__bf16)s3.y; g[6] = (__bf16)s3.z; g[7] = (__bf16)s3.w;
  *(bf16x8*)(Ab + wo1) = g;
}

// Grouped GEMM. A gathered per-lane from fp32 x (no xp buffer -> 34MB ws),
// reg-staged: global_load_dwordx4 x4 -> cvt once/tile -> 2x ds_write_b128
// into bf16 LDS with XOR swizzle chunk^=(row>>1)&3 (T2, both sides).
// B via global_load_lds with PRE-SWIZZLED per-lane global source (m173):
// same XOR, permutes 16B pieces within a 64B segment (coalescing unchanged),
// linear LDS dest receives the swizzled layout; reads use the same XOR.
// -> both A and B fragment ds_read_b128 are <=2-way (free, m136).
// Pipeline: 3 LDS buffers, 2 barriers/iter, counted vmcnt(8): B-DMA has
// 2-iter flight (depth-1 measured null, round 3), A-regs 1-iter, cvt one
// iter ahead of consumption. FIFO: entering iter t outstanding =
// {B(t):2, A(t+1):4, B(t+1):2}; issue 6 -> 14; vmcnt(8) forces B(t)+A(t+1).
// lgkmcnt(0) before barrier #2: raw s_barrier does NOT drain LDS writes --
// required for cross-wave visibility of cvt_write's ds_writes.
__global__ __launch_bounds__(256) void gemm_kernel(
    const float* __restrict__ x, const ushort* __restrict__ mixedW,
    const int* __restrict__ perm, const int* __restrict__ counts,
    const float* __restrict__ bias, float* __restrict__ out) {
  // XCD-aware swizzle (T1): contiguous work chunks per XCD. nwg = 2560, %8==0.
  int nwg = gridDim.x * gridDim.y;
  int lin = blockIdx.y * gridDim.x + blockIdx.x;
  int cpx = nwg >> 3;
  int work = (lin & 7) * cpx + (lin >> 3);
  int bx = work & 3;                        // gridDim.x == 4
  int by = work >> 2;

  int s = by / TPS;
  int tt = by - s * TPS;
  int count = counts[s * CSTR];
  int r0 = tt * BM;
  if (r0 >= count) return;        // dead tile (block-uniform)
  int rows = min(BM, count - r0);
  int n0 = bx * BN;

  __shared__ __align__(16) ushort Alds[3 * TILE_US];  // 24KB bf16, swizzled
  __shared__ __align__(16) ushort Blds[3 * TILE_US];  // 24KB bf16, swizzled
  __shared__ int prow[BM];

  int tid = threadIdx.x;
  int lane = tid & 63;
  int wave = tid >> 6;

  if (tid < BM) prow[tid] = perm[s * CAP + r0 + min(tid, rows - 1)];

  int chunk = lane & 3;                 // 16B (8 bf16 / 8 fp32) k-chunk
  int cxor = (lane >> 3) & 3;           // = (row>>1)&3 for staging rows
  // --- A staging: per lane, 2 rows (pass p=0,1), 1 chunk each.
  const float* agp0;
  const float* agp1;
  int awoff0, awoff1;
  {
    int rl0 = wave * 32 + (lane >> 2);          // pass 0 local row
    int rl1 = rl0 + 16;                         // pass 1 local row
    int pr0 = perm[s * CAP + r0 + min(rl0, rows - 1)];
    int pr1 = perm[s * CAP + r0 + min(rl1, rows - 1)];
    agp0 = x + (size_t)pr0 * DIN + chunk * 8;
    agp1 = x + (size_t)pr1 * DIN + chunk * 8;
    int ac = chunk ^ cxor;                      // swizzled chunk slot
    awoff0 = rl0 * 32 + ac * 8;                 // ushort units
    awoff1 = rl1 * 32 + ac * 8;
  }
  // --- B staging: gload_lds, pre-swizzled global source.
  const ushort* bgp0;
  const ushort* bgp1;
  int boff0, boff1;
  {
    int bkc = (chunk ^ cxor) * 8;               // fetch the chunk that the
    int row0 = (wave * 16) + (lane >> 2);       // linear dest slot expects
    int row1 = row0 + 64;
    bgp0 = mixedW + (size_t)s * (DOUT * DIN) + (size_t)(n0 + row0) * DIN + bkc;
    bgp1 = mixedW + (size_t)s * (DOUT * DIN) + (size_t)(n0 + row1) * DIN + bkc;
    boff0 = wave * 512;                         // region = wave
    boff1 = (4 + wave) * 512;                   // region = wave+4
  }

  floatx4 acc[4][4];
#pragma unroll
  for (int mt = 0; mt < 4; mt++)
#pragma unroll
    for (int nt = 0; nt < 4; nt++) acc[mt][nt] = {0.f, 0.f, 0.f, 0.f};

  int wm = wave >> 1, wn = wave & 1;
  int m15 = lane & 15, quad = lane >> 4;
  // Fragment read offsets (swizzled): row stride 32 ushorts, i stride 512.
  int rxor = (m15 >> 1) & 3;
  int rcol = (quad ^ rxor) * 8;
  int aro = (wm * 64 + m15) * 32 + rcol;
  int bro = (wn * 64 + m15) * 32 + rcol;

  float4 p0, p1, p2, p3, q0, q1, q2, q3;

  // Prologue: A0,B0 -> buf0; A1,B1 -> buf1; cvt A0 early.
  gload_a(agp0, agp1, 0, p0, p1, p2, p3);
  async_load16(bgp0, Blds + boff0);
  async_load16(bgp1, Blds + boff1);
  gload_a(agp0, agp1, 1, q0, q1, q2, q3);
  async_load16(bgp0 + BK, Blds + TILE_US + boff0);
  async_load16(bgp1 + BK, Blds + TILE_US + boff1);
  asm volatile("s_waitcnt vmcnt(8)" ::: "memory");   // A0 regs landed
  cvt_write(Alds, awoff0, awoff1, p0, p1, p2, p3);   // A0 -> buf0

#define ITER(T, C0, C1, C2, C3, N0, N1, N2, N3)                        \
  {                                                                    \
    if ((T) + 2 < NKT) {                                               \
      int c2 = b3(c0 + 2);                                             \
      gload_a(agp0, agp1, (T) + 2, N0, N1, N2, N3);                    \
      async_load16(bgp0 + ((T) + 2) * BK, Blds + c2 * TILE_US + boff0);\
      async_load16(bgp1 + ((T) + 2) * BK, Blds + c2 * TILE_US + boff1);\
      asm volatile("s_waitcnt vmcnt(8)" ::: "memory");                 \
    } else if ((T) == NKT - 2) {                                       \
      asm volatile("s_waitcnt vmcnt(2)" ::: "memory");                 \
    } else {                                                           \
      asm volatile("s_waitcnt vmcnt(0)" ::: "memory");                 \
    }                                                                  \
    __builtin_amdgcn_s_barrier();                                      \
    __builtin_amdgcn_sched_barrier(0);                                 \
    if ((T) + 1 < NKT)                                                 \
      cvt_write(Alds + b3(c0 + 1) * TILE_US, awoff0, awoff1,           \
                C0, C1, C2, C3);                                       \
    {                                                                  \
      const ushort* Ab = Alds + c0 * TILE_US;                          \
      const ushort* Bb = Blds + c0 * TILE_US;                          \
      bf16x8 af[4], bfm[4];                                            \
      _Pragma("unroll")                                                \
      for (int i = 0; i < 4; i++) {                                    \
        af[i]  = *(const bf16x8*)(Ab + aro + i * 512);                 \
        bfm[i] = *(const bf16x8*)(Bb + bro + i * 512);                 \
      }                                                                \
      _Pragma("unroll")                                                \
      for (int mt = 0; mt < 4; mt++)                                   \
        _Pragma("unroll")                                              \
        for (int nt = 0; nt < 4; nt++)                                 \
          acc[mt][nt] = __builtin_amdgcn_mfma_f32_16x16x32_bf16(       \
              af[mt], bfm[nt], acc[mt][nt], 0, 0, 0);                  \
    }                                                                  \
    asm volatile("s_waitcnt lgkmcnt(0)" ::: "memory");                 \
    __builtin_amdgcn_sched_barrier(0);                                 \
    __builtin_amdgcn_s_barrier();                                      \
    c0 = b3(c0 + 1);                                                   \
  }

  int c0 = 0;
  for (int t = 0; t < NKT; t += 2) {
    ITER(t,     q0, q1, q2, q3, p0, p1, p2, p3);  // cvt A(t+1)=q, load A(t+2)->p
    ITER(t + 1, p0, p1, p2, p3, q0, q1, q2, q3);  // cvt A(t+2)=p, load A(t+3)->q
  }
#undef ITER

  // Epilogue: C/D layout col=lane&15 (o), row=quad*4+reg (x-row in tile)
  float bv[4];
#pragma unroll
  for (int nt = 0; nt < 4; nt++) bv[nt] = bias[n0 + wn * 64 + nt * 16 + m15];

#pragma unroll
  for (int mt = 0; mt < 4; mt++) {
    int rb = wm * 64 + mt * 16 + quad * 4;
    int pr[4];
#pragma unroll
    for (int r = 0; r < 4; r++) pr[r] = prow[rb + r];
#pragma unroll
    for (int nt = 0; nt < 4; nt++) {
      int col = n0 + wn * 64 + nt * 16 + m15;
#pragma unroll
      for (int r = 0; r < 4; r++) {
        if (rb + r < rows)
          out[(size_t)pr[r] * DOUT + col] = acc[mt][nt][r] + bv[nt];
      }
    }
  }
}

extern "C" void kernel_launch(void* const* d_in, const int* in_sizes, int n_in,
                              void* d_out, int out_size, void* d_ws,
                              size_t ws_size, hipStream_t stream) {
  const float* x     = (const float*)d_in[0];
  const float* coeff = (const float*)d_in[1];
  const int*   bidx  = (const int*)d_in[2];
  const float* W     = (const float*)d_in[3];
  const float* bias  = (const float*)d_in[4];
  float* out = (float*)d_out;

  char* ws = (char*)d_ws;
  int* counts    = (int*)ws;                                  // 8 KB (padded)
  int* perm      = (int*)(ws + NS * CSTR * 4);                // 320 KB
  ushort* mixedW = (ushort*)(ws + NS * CSTR * 4 + NS * CAP * 4);  // 33.5 MB
  // total workspace ~34 MB: keeps the re-poison overhead at round-4 level

  hipMemsetAsync(counts, 0, NS * CSTR * sizeof(int), stream);
  hipLaunchKernelGGL(scatter_kernel, dim3(NA / 256), dim3(256), 0, stream,
                     bidx, counts, perm);
  hipLaunchKernelGGL(mixw_kernel, dim3(DOUT * DIN / 2048, 8), dim3(256), 0,
                     stream, W, coeff, mixedW);
  hipLaunchKernelGGL(gemm_kernel, dim3(DOUT / BN, NS * TPS), dim3(256), 0,
                     stream, x, mixedW, perm, counts, bias, out);
}

// Round 7
// 330.964 us; speedup vs baseline: 1.0816x; 1.0377x over previous
//
#include <hip/hip_runtime.h>
#include <hip/hip_bf16.h>

#define NA   65536
#define DIN  512
#define DOUT 512
#define NE   8
#define NS   64
#define CAP  1280   // per-system perm capacity (count ~ 1024 +- 32)
#define BM   128
#define BN   128
#define BK   32
#define TPS  (CAP / BM)   // row tiles per system = 10
#define NKT  (DIN / BK)   // 16 K-tiles
#define CSTR 32           // counts stride (ints): one 128B line per system
#define TILE_US 4096      // ushorts per 8KB LDS tile (BM*BK)
#define NSCAT (NA / 256)  // 256 scatter blocks

typedef __attribute__((ext_vector_type(8))) __bf16 bf16x8;
typedef __attribute__((ext_vector_type(4))) float floatx4;

__device__ __forceinline__ void async_load16(const void* g, void* l) {
  __builtin_amdgcn_global_load_lds(
      (__attribute__((address_space(1))) void*)(void*)g,
      (__attribute__((address_space(3))) void*)l,
      16, 0, 0);
}

// Merged prep: blocks [0,256) bucket atoms by system (scatter); blocks
// [256,1280) compute mixedW. Independent work -> one launch, one less gap.
__global__ void prep_kernel(const int* __restrict__ bidx,
                            int* __restrict__ counts,
                            int* __restrict__ perm,
                            const float* __restrict__ W,
                            const float* __restrict__ coeff,
                            ushort* __restrict__ mixedW) {
  __shared__ int hist[NS];
  __shared__ int base[NS];
  int t = threadIdx.x;
  if (blockIdx.x < NSCAT) {
    // ---- scatter ----
    if (t < NS) hist[t] = 0;
    __syncthreads();
    int n = blockIdx.x * 256 + t;
    int s = bidx[n];
    int rank = atomicAdd(&hist[s], 1);
    __syncthreads();
    if (t < NS && hist[t] > 0) base[t] = atomicAdd(&counts[t * CSTR], hist[t]);
    __syncthreads();
    perm[s * CAP + base[s] + rank] = n;
  } else {
    // ---- mixw: mixedW[s][o][i] = sum_e coeff[s][e]*W[e][o][i], bf16 ----
    int bx = blockIdx.x - NSCAT;
    int base_i = (bx & 127) * 2048 + t * 8;
    float w[NE][8];
#pragma unroll
    for (int e = 0; e < NE; e++) {
      const float4* p = (const float4*)(W + e * (DOUT * DIN) + base_i);
      float4 a = p[0], b = p[1];
      w[e][0] = a.x; w[e][1] = a.y; w[e][2] = a.z; w[e][3] = a.w;
      w[e][4] = b.x; w[e][5] = b.y; w[e][6] = b.z; w[e][7] = b.w;
    }
    int s0 = (bx >> 7) * 8;
    for (int si = 0; si < 8; si++) {
      int s = s0 + si;
      float o[8] = {0, 0, 0, 0, 0, 0, 0, 0};
#pragma unroll
      for (int e = 0; e < NE; e++) {
        float c = coeff[s * NE + e];
#pragma unroll
        for (int j = 0; j < 8; j++) o[j] += c * w[e][j];
      }
      union { bf16x8 v; uint4 u; } cv;
#pragma unroll
      for (int j = 0; j < 8; j++) cv.v[j] = (__bf16)o[j];
      *(uint4*)(mixedW + (size_t)s * (DOUT * DIN) + base_i) = cv.u;
    }
  }
}

__device__ __forceinline__ void gload_a(const float* g0, const float* g1,
                                        int kt, float4* d) {
  const float* a0 = g0 + kt * BK;
  const float* a1 = g1 + kt * BK;
  d[0] = *(const float4*)(a0);
  d[1] = *(const float4*)(a0 + 4);
  d[2] = *(const float4*)(a1);
  d[3] = *(const float4*)(a1 + 4);
}

__device__ __forceinline__ void cvt_write(ushort* Ab, int wo0, int wo1,
                                          const float4* d) {
  bf16x8 h;
  h[0] = (__bf16)d[0].x; h[1] = (__bf16)d[0].y; h[2] = (__bf16)d[0].z; h[3] = (__bf16)d[0].w;
  h[4] = (__bf16)d[1].x; h[5] = (__bf16)d[1].y; h[6] = (__bf16)d[1].z; h[7] = (__bf16)d[1].w;
  *(bf16x8*)(Ab + wo0) = h;
  bf16x8 g;
  g[0] = (__bf16)d[2].x; g[1] = (__bf16)d[2].y; g[2] = (__bf16)d[2].z; g[3] = (__bf16)d[2].w;
  g[4] = (__bf16)d[3].x; g[5] = (__bf16)d[3].y; g[6] = (__bf16)d[3].z; g[7] = (__bf16)d[3].w;
  *(bf16x8*)(Ab + wo1) = g;
}

// Grouped GEMM, depth-2 BOTH streams. A gathered per-lane from fp32 x,
// reg-staged via 3 ROTATING register sets As[3] (full unroll -> static
// indices): iter t issues A(t+3), cvt-writes A(t+1) (issued at t-2, 2-iter
// flight -- the r6 version only had 1-iter flight on A and stalled at
// vmcnt every iteration). B via global_load_lds, pre-swizzled source,
// 2-iter flight. FIFO entering iter t: [B(t):2, A(t+1):4, B(t+1):2,
// A(t+2):4]=12; issue B(t+2) -> 14; vmcnt(8) retires exactly B(t)+A(t+1).
// LDS XOR swizzle chunk^=(row>>1)&3 both sides (r6: conflicts 15.5M -> 0).
// lgkmcnt(0) before barrier2 for cross-wave cvt ds_write visibility.
__global__ __launch_bounds__(256) void gemm_kernel(
    const float* __restrict__ x, const ushort* __restrict__ mixedW,
    const int* __restrict__ perm, const int* __restrict__ counts,
    const float* __restrict__ bias, float* __restrict__ out) {
  // XCD-aware swizzle (T1): contiguous work chunks per XCD. nwg = 2560, %8==0.
  int nwg = gridDim.x * gridDim.y;
  int lin = blockIdx.y * gridDim.x + blockIdx.x;
  int cpx = nwg >> 3;
  int work = (lin & 7) * cpx + (lin >> 3);
  int bx = work & 3;                        // gridDim.x == 4
  int by = work >> 2;

  int s = by / TPS;
  int tt = by - s * TPS;
  int count = counts[s * CSTR];
  int r0 = tt * BM;
  if (r0 >= count) return;        // dead tile (block-uniform)
  int rows = min(BM, count - r0);
  int n0 = bx * BN;

  __shared__ __align__(16) ushort Alds[3 * TILE_US];  // 24KB bf16, swizzled
  __shared__ __align__(16) ushort Blds[3 * TILE_US];  // 24KB bf16, swizzled
  __shared__ int prow[BM];

  int tid = threadIdx.x;
  int lane = tid & 63;
  int wave = tid >> 6;

  if (tid < BM) prow[tid] = perm[s * CAP + r0 + min(tid, rows - 1)];

  int chunk = lane & 3;                 // 16B (8 bf16 / 8 fp32) k-chunk
  int cxor = (lane >> 3) & 3;           // = (row>>1)&3 for staging rows
  // --- A staging: per lane, 2 rows, 1 chunk each.
  const float* agp0;
  const float* agp1;
  int awoff0, awoff1;
  {
    int rl0 = wave * 32 + (lane >> 2);
    int rl1 = rl0 + 16;
    int pr0 = perm[s * CAP + r0 + min(rl0, rows - 1)];
    int pr1 = perm[s * CAP + r0 + min(rl1, rows - 1)];
    agp0 = x + (size_t)pr0 * DIN + chunk * 8;
    agp1 = x + (size_t)pr1 * DIN + chunk * 8;
    int ac = chunk ^ cxor;
    awoff0 = rl0 * 32 + ac * 8;
    awoff1 = rl1 * 32 + ac * 8;
  }
  // --- B staging: gload_lds, pre-swizzled global source (m173).
  const ushort* bgp0;
  const ushort* bgp1;
  int boff0, boff1;
  {
    int bkc = (chunk ^ cxor) * 8;
    int row0 = (wave * 16) + (lane >> 2);
    int row1 = row0 + 64;
    bgp0 = mixedW + (size_t)s * (DOUT * DIN) + (size_t)(n0 + row0) * DIN + bkc;
    bgp1 = mixedW + (size_t)s * (DOUT * DIN) + (size_t)(n0 + row1) * DIN + bkc;
    boff0 = wave * 512;
    boff1 = (4 + wave) * 512;
  }

  floatx4 acc[4][4];
#pragma unroll
  for (int mt = 0; mt < 4; mt++)
#pragma unroll
    for (int nt = 0; nt < 4; nt++) acc[mt][nt] = {0.f, 0.f, 0.f, 0.f};

  int wm = wave >> 1, wn = wave & 1;
  int m15 = lane & 15, quad = lane >> 4;
  int rxor = (m15 >> 1) & 3;
  int rcol = (quad ^ rxor) * 8;
  int aro = (wm * 64 + m15) * 32 + rcol;
  int bro = (wn * 64 + m15) * 32 + rcol;

  float4 As[3][4];  // rotating A reg sets; A(j) lives in As[(j-1)%3]

  // Prologue. Issue order (FIFO): A0:4, B0:2, A1:4, B1:2, A2:4 = 16.
  gload_a(agp0, agp1, 0, As[2]);                 // A0 (temp in S2)
  async_load16(bgp0, Blds + boff0);              // B0 -> buf0
  async_load16(bgp1, Blds + boff1);
  gload_a(agp0, agp1, 1, As[0]);                 // A1 -> S0
  async_load16(bgp0 + BK, Blds + TILE_US + boff0);  // B1 -> buf1
  async_load16(bgp1 + BK, Blds + TILE_US + boff1);
  gload_a(agp0, agp1, 2, As[1]);                 // A2 -> S1
  asm volatile("s_waitcnt vmcnt(12)" ::: "memory");  // A0 landed
  cvt_write(Alds, awoff0, awoff1, As[2]);        // A0 -> buf0

#pragma unroll
  for (int t = 0; t < NKT; ++t) {
    const int cb = t % 3;          // compute buffer (tile t)
    const int wb = (t + 1) % 3;    // cvt target buffer (tile t+1)
    const int nb = (t + 2) % 3;    // B DMA target buffer (tile t+2)
    if (t + 2 < NKT) {
      async_load16(bgp0 + (t + 2) * BK, Blds + nb * TILE_US + boff0);
      async_load16(bgp1 + (t + 2) * BK, Blds + nb * TILE_US + boff1);
      asm volatile("s_waitcnt vmcnt(8)" ::: "memory");   // B(t)+A(t+1) landed
    } else if (t == NKT - 2) {
      asm volatile("s_waitcnt vmcnt(2)" ::: "memory");
    } else {
      asm volatile("s_waitcnt vmcnt(0)" ::: "memory");
    }
    __builtin_amdgcn_s_barrier();        // tile t resident for all waves
    __builtin_amdgcn_sched_barrier(0);   // no ds_read hoisted above barrier

    {
      const ushort* Ab = Alds + cb * TILE_US;
      const ushort* Bb = Blds + cb * TILE_US;
      bf16x8 af[4], bfm[4];
#pragma unroll
      for (int i = 0; i < 4; i++) {
        af[i]  = *(const bf16x8*)(Ab + aro + i * 512);
        bfm[i] = *(const bf16x8*)(Bb + bro + i * 512);
      }
#pragma unroll
      for (int mt = 0; mt < 4; mt++)
#pragma unroll
        for (int nt = 0; nt < 4; nt++)
          acc[mt][nt] = __builtin_amdgcn_mfma_f32_16x16x32_bf16(
              af[mt], bfm[nt], acc[mt][nt], 0, 0, 0);
    }
    if (t + 1 < NKT)                      // A(t+1): issued at t-2, landed
      cvt_write(Alds + wb * TILE_US, awoff0, awoff1, As[t % 3]);
    if (t + 3 < NKT)                      // reuse the set just consumed
      gload_a(agp0, agp1, t + 3, As[(t + 2) % 3]);
    asm volatile("s_waitcnt lgkmcnt(0)" ::: "memory");  // cvt writes visible
    __builtin_amdgcn_sched_barrier(0);
    __builtin_amdgcn_s_barrier();        // all waves done reading buf cb
  }

  // Epilogue: C/D layout col=lane&15 (o), row=quad*4+reg (x-row in tile)
  float bv[4];
#pragma unroll
  for (int nt = 0; nt < 4; nt++) bv[nt] = bias[n0 + wn * 64 + nt * 16 + m15];

#pragma unroll
  for (int mt = 0; mt < 4; mt++) {
    int rb = wm * 64 + mt * 16 + quad * 4;
    int pr[4];
#pragma unroll
    for (int r = 0; r < 4; r++) pr[r] = prow[rb + r];
#pragma unroll
    for (int nt = 0; nt < 4; nt++) {
      int col = n0 + wn * 64 + nt * 16 + m15;
#pragma unroll
      for (int r = 0; r < 4; r++) {
        if (rb + r < rows)
          out[(size_t)pr[r] * DOUT + col] = acc[mt][nt][r] + bv[nt];
      }
    }
  }
}

extern "C" void kernel_launch(void* const* d_in, const int* in_sizes, int n_in,
                              void* d_out, int out_size, void* d_ws,
                              size_t ws_size, hipStream_t stream) {
  const float* x     = (const float*)d_in[0];
  const float* coeff = (const float*)d_in[1];
  const int*   bidx  = (const int*)d_in[2];
  const float* W     = (const float*)d_in[3];
  const float* bias  = (const float*)d_in[4];
  float* out = (float*)d_out;

  char* ws = (char*)d_ws;
  int* counts    = (int*)ws;                                  // 8 KB (padded)
  int* perm      = (int*)(ws + NS * CSTR * 4);                // 320 KB
  ushort* mixedW = (ushort*)(ws + NS * CSTR * 4 + NS * CAP * 4);  // 33.5 MB
  // total workspace ~34 MB (poison overhead scales with ws size)

  hipMemsetAsync(counts, 0, NS * CSTR * sizeof(int), stream);
  hipLaunchKernelGGL(prep_kernel, dim3(NSCAT + 128 * 8), dim3(256), 0, stream,
                     bidx, counts, perm, W, coeff, mixedW);
  hipLaunchKernelGGL(gemm_kernel, dim3(DOUT / BN, NS * TPS), dim3(256), 0,
                     stream, x, mixedW, perm, counts, bias, out);
}